// Round 9
// baseline (779.476 us; speedup 1.0000x reference)
//
#include <hip/hip_runtime.h>

// QLinear: y[b,s,o] = sum_i x[b,s,i] * W_q[o,i] * scale[o]
#define M_DIM 8192    // BATCH*SEQ
#define N_DIM 11008   // OUT_F
#define K_DIM 4096    // IN_F

#define BM 256
#define BN 256
#define BK 64
#define NT (K_DIM / BK)            // 64 K-tiles
#define NBN (N_DIM / BN)           // 43
#define NWG ((M_DIM / BM) * NBN)   // 1376 (divisible by 8)

typedef __bf16 bf16x8 __attribute__((ext_vector_type(8)));
typedef float f32x16 __attribute__((ext_vector_type(16)));
typedef unsigned short ushort8 __attribute__((ext_vector_type(8)));

__device__ __forceinline__ unsigned short f2bf(float f) {
  unsigned u = __builtin_bit_cast(unsigned, f);
  u += 0x7fffu + ((u >> 16) & 1u);
  return (unsigned short)(u >> 16);
}

__device__ __forceinline__ void async_copy16(const void* g, void* l) {
  __builtin_amdgcn_global_load_lds(
      (const __attribute__((address_space(1))) void*)g,
      (__attribute__((address_space(3))) void*)l, 16, 0, 0);
}

// ---- conversion kernels ----
__global__ __launch_bounds__(256) void cvt_x_kernel(const float* __restrict__ in,
                                                    unsigned short* __restrict__ outp) {
  const int idx = blockIdx.x * 256 + threadIdx.x;
  const float4* in4 = (const float4*)in;
  float4 a = in4[2 * idx], b = in4[2 * idx + 1];
  ushort8 o;
  o[0] = f2bf(a.x); o[1] = f2bf(a.y); o[2] = f2bf(a.z); o[3] = f2bf(a.w);
  o[4] = f2bf(b.x); o[5] = f2bf(b.y); o[6] = f2bf(b.z); o[7] = f2bf(b.w);
  ((ushort8*)outp)[idx] = o;
}

__global__ __launch_bounds__(256) void cvt_w_kernel(const int* __restrict__ in,
                                                    unsigned short* __restrict__ outp) {
  const int idx = blockIdx.x * 256 + threadIdx.x;
  const int4* in4 = (const int4*)in;
  int4 a = in4[2 * idx], b = in4[2 * idx + 1];
  ushort8 o;  // values 0..15: exact in bf16
  o[0] = f2bf((float)a.x); o[1] = f2bf((float)a.y);
  o[2] = f2bf((float)a.z); o[3] = f2bf((float)a.w);
  o[4] = f2bf((float)b.x); o[5] = f2bf((float)b.y);
  o[6] = f2bf((float)b.z); o[7] = f2bf((float)b.w);
  ((ushort8*)outp)[idx] = o;
}

// Stage one 128x64 half-tile (16 KiB): linear LDS dest, inverse-swizzled
// global source (rule #21 both-sides swizzle). 2 gload_lds -> vmcnt +2.
__device__ __forceinline__ void stage_half(const unsigned short* __restrict__ P,
                                           int grow0, int k0, char* dest, int tid) {
  const int rl = tid >> 3;                            // 0..63
  const int kb = ((tid & 7) * 16) ^ ((rl & 7) << 4);  // pre-swizzled k-byte
  async_copy16(&P[(size_t)(grow0 + rl) * K_DIM + k0 + (kb >> 1)], dest + tid * 16);
  async_copy16(&P[(size_t)(grow0 + 64 + rl) * K_DIM + k0 + (kb >> 1)],
               dest + 8192 + tid * 16);
}

// ---- main GEMM: 256x256, BK=64, 8 waves, R5 structure (1 barrier/K-tile,
// top prefetch, bottom vmcnt, compiler-scheduled interleave) with
// v_mfma_f32_32x32x16_bf16 (2495 TF rate vs 2176 for 16x16x32; m119). ----
// Per wave: 128x64 output as 4x2 grid of 32x32 tiles; K in 4 quarters of 16.
// A-frag: row=lane&31, k=(lane>>5)*8+j.  B-frag: col=lane&31, same k.
// C/D: col=lane&31, row=(reg&3)+8*(reg>>2)+4*(lane>>5)  [m74/m101-verified].
__global__ __launch_bounds__(512, 1) void gemm_bf16(
    const unsigned short* __restrict__ A, const unsigned short* __restrict__ B,
    const float* __restrict__ scale, float* __restrict__ out) {
  __shared__ __align__(16) unsigned short sm[65536];  // 128 KiB, 2 buffers
  char* smw = (char*)sm;

  const int tid = threadIdx.x;
  const int lane = tid & 63;
  const int wv = tid >> 6;
  const int wr = wv >> 2, wc = wv & 3;   // 2x4 wave grid, 128x64 out/wave
  const int l31 = lane & 31;             // A-row / B-col within 32
  const int h = lane >> 5;               // k-half selector
  const int swz = (l31 & 7) << 4;        // read-side XOR key (bytes)

  int id = blockIdx.x;                   // T1: bijective XCD swizzle
  id = (id & 7) * (NWG / 8) + (id >> 3);
  const int bn = (id % NBN) * BN;
  const int bm = (id / NBN) * BM;

  const int brow0 = (wc & 1) * 64 + l31;  // B row (=out col) within its half

  f32x16 acc[4][2] = {};                  // 128 regs

  // prologue: stage tile 0 into buffer 0; vmcnt BEFORE barrier (visibility)
  stage_half(A, bm,       0, smw,         tid);
  stage_half(A, bm + 128, 0, smw + 16384, tid);
  stage_half(B, bn,       0, smw + 32768, tid);
  stage_half(B, bn + 128, 0, smw + 49152, tid);
  asm volatile("s_waitcnt vmcnt(0)" ::: "memory");
  __builtin_amdgcn_s_barrier();

#pragma unroll 1
  for (int t = 0; t < NT; ++t) {
    const int cur = t & 1;
    const char* Abuf = smw + cur * 65536 + wr * 16384;
    const char* Bbuf = smw + cur * 65536 + 32768 + (wc >> 1) * 16384;

    // Prefetch tile t+1 into buf[cur^1]. WAR-safe: its readers finished at
    // tile t-1 (certified by the bottom barrier of t-1).
    if (t + 1 < NT) {
      char* nb = smw + (cur ^ 1) * 65536;
      const int k1 = (t + 1) * BK;
      stage_half(A, bm,       k1, nb,         tid);
      stage_half(A, bm + 128, k1, nb + 16384, tid);
      stage_half(B, bn,       k1, nb + 32768, tid);
      stage_half(B, bn + 128, k1, nb + 49152, tid);
    }

    // ---- compute: 4 K-quarters, each {4 A-reads + 2 B-reads -> 8 MFMA};
    // compiler pipelines reads of kq+1 under MFMAs of kq. ----
#pragma unroll
    for (int kq = 0; kq < 4; ++kq) {
      const int kb = (kq * 32 + h * 16) ^ swz;
      bf16x8 af[4], bf[2];
#pragma unroll
      for (int mi = 0; mi < 4; ++mi)
        af[mi] = *(const bf16x8*)(Abuf + (mi * 32 + l31) * 128 + kb);
#pragma unroll
      for (int ni = 0; ni < 2; ++ni)
        bf[ni] = *(const bf16x8*)(Bbuf + (brow0 + ni * 32) * 128 + kb);
#pragma unroll
      for (int mi = 0; mi < 4; ++mi)
#pragma unroll
        for (int ni = 0; ni < 2; ++ni)
          acc[mi][ni] = __builtin_amdgcn_mfma_f32_32x32x16_bf16(
              af[mi], bf[ni], acc[mi][ni], 0, 0, 0);
    }

    // Bottom sync: drain own prefetch (issued a full tile ago -> hidden),
    // THEN barrier => all waves' tile-t+1 data visible + tile-t reads done.
    if (t + 1 < NT) {
      asm volatile("s_waitcnt vmcnt(0)" ::: "memory");
      __builtin_amdgcn_s_barrier();
    }
  }

  // epilogue: 32x32 C/D layout, scale fused
  const int ocol0 = bn + wc * 64 + l31;
  const int orow0 = bm + wr * 128 + 4 * h;
#pragma unroll
  for (int ni = 0; ni < 2; ++ni) {
    const float s = scale[ocol0 + ni * 32];
#pragma unroll
    for (int mi = 0; mi < 4; ++mi) {
#pragma unroll
      for (int reg = 0; reg < 16; ++reg) {
        const int row = orow0 + mi * 32 + (reg & 3) + 8 * (reg >> 2);
        out[(size_t)row * N_DIM + ocol0 + ni * 32] = acc[mi][ni][reg] * s;
      }
    }
  }
}

// ---- fallback (only if ws too small): fp32 LDS-tiled, correct but slow ----
__global__ __launch_bounds__(256) void gemm_fallback(
    const float* __restrict__ X, const int* __restrict__ Wq,
    const float* __restrict__ scale, float* __restrict__ out) {
  __shared__ float Xs[64][17];
  __shared__ float Ws[64][17];
  const int tid = threadIdx.x;
  const int tn = blockIdx.x % (N_DIM / 64);
  const int tm = blockIdx.x / (N_DIM / 64);
  const int tr = tid >> 4, tc = tid & 15;
  float acc[4][4] = {};
  for (int k0 = 0; k0 < K_DIM; k0 += 16) {
#pragma unroll
    for (int i = 0; i < 4; ++i) {
      int idx = tid + i * 256;
      int r = idx >> 4, c = idx & 15;
      Xs[r][c] = X[(size_t)(tm * 64 + r) * K_DIM + k0 + c];
      Ws[r][c] = (float)Wq[(size_t)(tn * 64 + r) * K_DIM + k0 + c];
    }
    __syncthreads();
#pragma unroll
    for (int kk = 0; kk < 16; ++kk)
#pragma unroll
      for (int i = 0; i < 4; ++i) {
        float a = Xs[tr * 4 + i][kk];
#pragma unroll
        for (int j = 0; j < 4; ++j) acc[i][j] += a * Ws[tc * 4 + j][kk];
      }
    __syncthreads();
  }
#pragma unroll
  for (int i = 0; i < 4; ++i)
#pragma unroll
    for (int j = 0; j < 4; ++j) {
      int row = tm * 64 + tr * 4 + i, col = tn * 64 + tc * 4 + j;
      out[(size_t)row * N_DIM + col] = acc[i][j] * scale[col];
    }
}

extern "C" void kernel_launch(void* const* d_in, const int* in_sizes, int n_in,
                              void* d_out, int out_size, void* d_ws, size_t ws_size,
                              hipStream_t stream) {
  const float* x = (const float*)d_in[0];
  const int* Wq = (const int*)d_in[1];
  const float* scale = (const float*)d_in[2];
  float* out = (float*)d_out;

  const size_t XN = (size_t)M_DIM * K_DIM;
  const size_t WN = (size_t)N_DIM * K_DIM;
  const size_t need = (XN + WN) * sizeof(unsigned short);

  if (ws_size >= need) {
    unsigned short* xbf = (unsigned short*)d_ws;
    unsigned short* wbf = xbf + XN;
    cvt_x_kernel<<<(unsigned)(XN / 2048), 256, 0, stream>>>(x, xbf);
    cvt_w_kernel<<<(unsigned)(WN / 2048), 256, 0, stream>>>(Wq, wbf);
    gemm_bf16<<<NWG, 512, 0, stream>>>(xbf, wbf, scale, out);
  } else {
    gemm_fallback<<<(N_DIM / 64) * (M_DIM / 64), 256, 0, stream>>>(x, Wq, scale, out);
  }
}

// Round 10
// 764.511 us; speedup vs baseline: 1.0196x; 1.0196x over previous
//
#include <hip/hip_runtime.h>

// QLinear: y[b,s,o] = sum_i x[b,s,i] * W_q[o,i] * scale[o]
#define M_DIM 8192    // BATCH*SEQ
#define N_DIM 11008   // OUT_F
#define K_DIM 4096    // IN_F

#define BM 256
#define BN 256
#define BK 64
#define NT (K_DIM / BK)            // 64 K-tiles
#define NBN (N_DIM / BN)           // 43
#define NWG ((M_DIM / BM) * NBN)   // 1376 (divisible by 8)

typedef __bf16 bf16x8 __attribute__((ext_vector_type(8)));
typedef float f32x16 __attribute__((ext_vector_type(16)));
typedef unsigned short ushort8 __attribute__((ext_vector_type(8)));

__device__ __forceinline__ unsigned short f2bf(float f) {
  unsigned u = __builtin_bit_cast(unsigned, f);
  u += 0x7fffu + ((u >> 16) & 1u);
  return (unsigned short)(u >> 16);
}

__device__ __forceinline__ void async_copy16(const void* g, void* l) {
  __builtin_amdgcn_global_load_lds(
      (const __attribute__((address_space(1))) void*)g,
      (__attribute__((address_space(3))) void*)l, 16, 0, 0);
}

// ---- conversion kernels ----
__global__ __launch_bounds__(256) void cvt_x_kernel(const float* __restrict__ in,
                                                    unsigned short* __restrict__ outp) {
  const int idx = blockIdx.x * 256 + threadIdx.x;
  const float4* in4 = (const float4*)in;
  float4 a = in4[2 * idx], b = in4[2 * idx + 1];
  ushort8 o;
  o[0] = f2bf(a.x); o[1] = f2bf(a.y); o[2] = f2bf(a.z); o[3] = f2bf(a.w);
  o[4] = f2bf(b.x); o[5] = f2bf(b.y); o[6] = f2bf(b.z); o[7] = f2bf(b.w);
  ((ushort8*)outp)[idx] = o;
}

__global__ __launch_bounds__(256) void cvt_w_kernel(const int* __restrict__ in,
                                                    unsigned short* __restrict__ outp) {
  const int idx = blockIdx.x * 256 + threadIdx.x;
  const int4* in4 = (const int4*)in;
  int4 a = in4[2 * idx], b = in4[2 * idx + 1];
  ushort8 o;  // values 0..15: exact in bf16
  o[0] = f2bf((float)a.x); o[1] = f2bf((float)a.y);
  o[2] = f2bf((float)a.z); o[3] = f2bf((float)a.w);
  o[4] = f2bf((float)b.x); o[5] = f2bf((float)b.y);
  o[6] = f2bf((float)b.z); o[7] = f2bf((float)b.w);
  ((ushort8*)outp)[idx] = o;
}

// Swizzle key now includes row bit 4: key(r) = (r&7) ^ ((r>>4)&1).
// Hypothesis under test: lanes 16 apart must land in different bank-slots
// for the 32x32 fragment read pattern (R9 showed 6.76e7 conflicts with the
// (r&7)-only key; the 16x16 pattern embedded lane>>4 in the k-offset).
// Stage one 128x64 half-tile (16 KiB): linear LDS dest, inverse-swizzled
// global source (rule #21 both-sides swizzle). 2 gload_lds -> vmcnt +2.
__device__ __forceinline__ void stage_half(const unsigned short* __restrict__ P,
                                           int grow0, int k0, char* dest, int tid) {
  const int rl = tid >> 3;                            // 0..63 (row; row+64 same key)
  const int key = (rl & 7) ^ ((rl >> 4) & 1);
  const int kb = ((tid & 7) * 16) ^ (key << 4);       // pre-swizzled k-byte
  async_copy16(&P[(size_t)(grow0 + rl) * K_DIM + k0 + (kb >> 1)], dest + tid * 16);
  async_copy16(&P[(size_t)(grow0 + 64 + rl) * K_DIM + k0 + (kb >> 1)],
               dest + 8192 + tid * 16);
}

// ---- main GEMM: 256x256, BK=64, 8 waves, R5 sync structure (1 barrier/
// K-tile, top prefetch spread across kq, bottom vmcnt(0) BEFORE barrier),
// v_mfma_f32_32x32x16_bf16 with bit4-aware swizzle + setprio clusters. ----
// A-frag: row=lane&31, k=(lane>>5)*8+j.  B-frag: col=lane&31, same k.
// C/D: col=lane&31, row=(reg&3)+8*(reg>>2)+4*(lane>>5)  [m74/m101-verified].
__global__ __launch_bounds__(512, 1) void gemm_bf16(
    const unsigned short* __restrict__ A, const unsigned short* __restrict__ B,
    const float* __restrict__ scale, float* __restrict__ out) {
  __shared__ __align__(16) unsigned short sm[65536];  // 128 KiB, 2 buffers
  char* smw = (char*)sm;

  const int tid = threadIdx.x;
  const int lane = tid & 63;
  const int wv = tid >> 6;
  const int wr = wv >> 2, wc = wv & 3;   // 2x4 wave grid, 128x64 out/wave
  const int l31 = lane & 31;             // A-row / B-col within 32
  const int h = lane >> 5;               // k-half selector
  // read-side key: row bits of the fragment row; mi*32 / ni*32 / (wc&1)*64
  // only touch bits >=5, so key depends on l31 alone.
  const int swz = (((l31 & 7) ^ ((l31 >> 4) & 1)) << 4);

  int id = blockIdx.x;                   // T1: bijective XCD swizzle
  id = (id & 7) * (NWG / 8) + (id >> 3);
  const int bn = (id % NBN) * BN;
  const int bm = (id / NBN) * BM;

  const int brow0 = (wc & 1) * 64 + l31;  // B row (=out col) within its half

  f32x16 acc[4][2] = {};                  // 128 regs

  // prologue: stage tile 0 into buffer 0; vmcnt BEFORE barrier (visibility)
  stage_half(A, bm,       0, smw,         tid);
  stage_half(A, bm + 128, 0, smw + 16384, tid);
  stage_half(B, bn,       0, smw + 32768, tid);
  stage_half(B, bn + 128, 0, smw + 49152, tid);
  asm volatile("s_waitcnt vmcnt(0)" ::: "memory");
  __builtin_amdgcn_s_barrier();

#pragma unroll 1
  for (int t = 0; t < NT; ++t) {
    const int cur = t & 1;
    const char* Abuf = smw + cur * 65536 + wr * 16384;
    const char* Bbuf = smw + cur * 65536 + 32768 + (wc >> 1) * 16384;
    char* nb = smw + (cur ^ 1) * 65536;
    const int k1 = (t + 1) * BK;
    const bool pf = (t + 1 < NT);

    // ---- compute: 4 K-quarters, each {4 A-reads + 2 B-reads -> 8 MFMA};
    // one prefetch stage_half issued per quarter (spread issue pressure);
    // compiler pipelines reads of kq+1 under MFMAs of kq. ----
#pragma unroll
    for (int kq = 0; kq < 4; ++kq) {
      const int kb = (kq * 32 + h * 16) ^ swz;
      bf16x8 af[4], bf[2];
#pragma unroll
      for (int mi = 0; mi < 4; ++mi)
        af[mi] = *(const bf16x8*)(Abuf + (mi * 32 + l31) * 128 + kb);
#pragma unroll
      for (int ni = 0; ni < 2; ++ni)
        bf[ni] = *(const bf16x8*)(Bbuf + (brow0 + ni * 32) * 128 + kb);
      if (pf) {
        if (kq == 0) stage_half(A, bm,       k1, nb,         tid);
        if (kq == 1) stage_half(A, bm + 128, k1, nb + 16384, tid);
        if (kq == 2) stage_half(B, bn,       k1, nb + 32768, tid);
        if (kq == 3) stage_half(B, bn + 128, k1, nb + 49152, tid);
      }
      __builtin_amdgcn_s_setprio(1);
#pragma unroll
      for (int mi = 0; mi < 4; ++mi)
#pragma unroll
        for (int ni = 0; ni < 2; ++ni)
          acc[mi][ni] = __builtin_amdgcn_mfma_f32_32x32x16_bf16(
              af[mi], bf[ni], acc[mi][ni], 0, 0, 0);
      __builtin_amdgcn_s_setprio(0);
    }

    // Bottom sync: drain own prefetch (issued up to a tile ago -> hidden),
    // THEN barrier => all waves' tile-t+1 data visible + tile-t reads done.
    if (pf) {
      asm volatile("s_waitcnt vmcnt(0)" ::: "memory");
      __builtin_amdgcn_s_barrier();
    }
  }

  // epilogue: 32x32 C/D layout, scale fused
  const int ocol0 = bn + wc * 64 + l31;
  const int orow0 = bm + wr * 128 + 4 * h;
#pragma unroll
  for (int ni = 0; ni < 2; ++ni) {
    const float s = scale[ocol0 + ni * 32];
#pragma unroll
    for (int mi = 0; mi < 4; ++mi) {
#pragma unroll
      for (int reg = 0; reg < 16; ++reg) {
        const int row = orow0 + mi * 32 + (reg & 3) + 8 * (reg >> 2);
        out[(size_t)row * N_DIM + ocol0 + ni * 32] = acc[mi][ni][reg] * s;
      }
    }
  }
}

// ---- fallback (only if ws too small): fp32 LDS-tiled, correct but slow ----
__global__ __launch_bounds__(256) void gemm_fallback(
    const float* __restrict__ X, const int* __restrict__ Wq,
    const float* __restrict__ scale, float* __restrict__ out) {
  __shared__ float Xs[64][17];
  __shared__ float Ws[64][17];
  const int tid = threadIdx.x;
  const int tn = blockIdx.x % (N_DIM / 64);
  const int tm = blockIdx.x / (N_DIM / 64);
  const int tr = tid >> 4, tc = tid & 15;
  float acc[4][4] = {};
  for (int k0 = 0; k0 < K_DIM; k0 += 16) {
#pragma unroll
    for (int i = 0; i < 4; ++i) {
      int idx = tid + i * 256;
      int r = idx >> 4, c = idx & 15;
      Xs[r][c] = X[(size_t)(tm * 64 + r) * K_DIM + k0 + c];
      Ws[r][c] = (float)Wq[(size_t)(tn * 64 + r) * K_DIM + k0 + c];
    }
    __syncthreads();
#pragma unroll
    for (int kk = 0; kk < 16; ++kk)
#pragma unroll
      for (int i = 0; i < 4; ++i) {
        float a = Xs[tr * 4 + i][kk];
#pragma unroll
        for (int j = 0; j < 4; ++j) acc[i][j] += a * Ws[tc * 4 + j][kk];
      }
    __syncthreads();
  }
#pragma unroll
  for (int i = 0; i < 4; ++i)
#pragma unroll
    for (int j = 0; j < 4; ++j) {
      int row = tm * 64 + tr * 4 + i, col = tn * 64 + tc * 4 + j;
      out[(size_t)row * N_DIM + col] = acc[i][j] * scale[col];
    }
}

extern "C" void kernel_launch(void* const* d_in, const int* in_sizes, int n_in,
                              void* d_out, int out_size, void* d_ws, size_t ws_size,
                              hipStream_t stream) {
  const float* x = (const float*)d_in[0];
  const int* Wq = (const int*)d_in[1];
  const float* scale = (const float*)d_in[2];
  float* out = (float*)d_out;

  const size_t XN = (size_t)M_DIM * K_DIM;
  const size_t WN = (size_t)N_DIM * K_DIM;
  const size_t need = (XN + WN) * sizeof(unsigned short);

  if (ws_size >= need) {
    unsigned short* xbf = (unsigned short*)d_ws;
    unsigned short* wbf = xbf + XN;
    cvt_x_kernel<<<(unsigned)(XN / 2048), 256, 0, stream>>>(x, xbf);
    cvt_w_kernel<<<(unsigned)(WN / 2048), 256, 0, stream>>>(Wq, wbf);
    gemm_bf16<<<NWG, 512, 0, stream>>>(xbf, wbf, scale, out);
  } else {
    gemm_fallback<<<(N_DIM / 64) * (M_DIM / 64), 256, 0, stream>>>(x, Wq, scale, out);
  }
}

// Round 11
// 514.787 us; speedup vs baseline: 1.5142x; 1.4851x over previous
//
#include <hip/hip_runtime.h>
#include <math.h>

// QLinear via int8: y = (sum_k xq[r][k]*Wq[c][k]) * sx[r] * scale[c]
// Wq in [0,16) is EXACT in i8; only x-quantization contributes error.
#define M_DIM 8192    // BATCH*SEQ
#define N_DIM 11008   // OUT_F
#define K_DIM 4096    // IN_F

#define BM 256
#define BN 256
#define BKB 64                     // K-bytes per tile (64 i8)
#define NT (K_DIM / BKB)           // 64 K-tiles
#define NBN (N_DIM / BN)           // 43
#define NWG ((M_DIM / BM) * NBN)   // 1376 (divisible by 8)

typedef int int4v __attribute__((ext_vector_type(4)));
typedef int int16v __attribute__((ext_vector_type(16)));

__device__ __forceinline__ void async_copy16(const void* g, void* l) {
  __builtin_amdgcn_global_load_lds(
      (const __attribute__((address_space(1))) void*)g,
      (__attribute__((address_space(3))) void*)l, 16, 0, 0);
}

// ---- x quantization: one block per row; per-row absmax -> i8 ----
__global__ __launch_bounds__(256) void quant_x(const float* __restrict__ x,
                                               signed char* __restrict__ xq,
                                               float* __restrict__ sx) {
  __shared__ float wred[4];
  const int row = blockIdx.x;
  const int tid = threadIdx.x;
  const float4* src = (const float4*)(x + (size_t)row * K_DIM) + tid * 4;
  float4 v0 = src[0], v1 = src[1], v2 = src[2], v3 = src[3];

  float m = 0.f;
#define MX4(V) m = fmaxf(m, fmaxf(fmaxf(fabsf(V.x), fabsf(V.y)), fmaxf(fabsf(V.z), fabsf(V.w))))
  MX4(v0); MX4(v1); MX4(v2); MX4(v3);
#undef MX4
#pragma unroll
  for (int off = 32; off >= 1; off >>= 1)
    m = fmaxf(m, __shfl_xor(m, off, 64));
  if ((tid & 63) == 0) wred[tid >> 6] = m;
  __syncthreads();
  float smax = fmaxf(fmaxf(wred[0], wred[1]), fmaxf(wred[2], wred[3]));
  smax = fmaxf(smax, 1e-20f);
  const float inv = 127.f / smax;

  int4v o;
#define Q4(V, G) o[G] = ((int)rintf(V.x * inv) & 255) | (((int)rintf(V.y * inv) & 255) << 8) | \
                        (((int)rintf(V.z * inv) & 255) << 16) | (((int)rintf(V.w * inv) & 255) << 24)
  Q4(v0, 0); Q4(v1, 1); Q4(v2, 2); Q4(v3, 3);
#undef Q4
  ((int4v*)(xq + (size_t)row * K_DIM))[tid] = o;
  if (tid == 0) sx[row] = smax / 127.f;
}

// ---- W pack: int32 (0..15) -> i8, 16 elems/thread ----
__global__ __launch_bounds__(256) void pack_w(const int* __restrict__ in,
                                              signed char* __restrict__ wq) {
  const int idx = blockIdx.x * 256 + threadIdx.x;
  const int4* in4 = (const int4*)in + (size_t)idx * 4;
  int4 a = in4[0], b = in4[1], c = in4[2], d = in4[3];
  int4v o;
  o[0] = a.x | (a.y << 8) | (a.z << 16) | (a.w << 24);
  o[1] = b.x | (b.y << 8) | (b.z << 16) | (b.w << 24);
  o[2] = c.x | (c.y << 8) | (c.z << 16) | (c.w << 24);
  o[3] = d.x | (d.y << 8) | (d.z << 16) | (d.w << 24);
  ((int4v*)wq)[idx] = o;
}

// Stage one 128x64B half-tile (8 KiB): linear LDS dest, inverse-swizzled
// global source. Swizzle key(r) = ((r>>1)^(r>>3))&3 on the 16B-chunk index
// spreads 32 lanes evenly over 8 bank-slots (64B rows). 1 gload_lds/thread.
__device__ __forceinline__ void stage_q(const signed char* __restrict__ P,
                                        int grow0, int k0b, char* dest, int tid) {
  const int rl = tid >> 2;                           // 0..127
  const int key = ((rl >> 1) ^ (rl >> 3)) & 3;
  const int kb = (((tid & 3) ^ key) << 4);           // pre-swizzled chunk byte
  async_copy16(&P[(size_t)(grow0 + rl) * K_DIM + k0b + kb], dest + tid * 16);
}

// ---- main GEMM: 256x256, BKB=64, 8 waves, R5/R10 sync skeleton,
// v_mfma_i32_32x32x32_i8 (4404 TOPS = 1.77x bf16; half the LDS traffic). ----
// A-frag row=lane&31; k-permutation cancels between A and B operands.
// C/D: col=lane&31, row=(reg&3)+8*(reg>>2)+4*(lane>>5) [shape-determined,
// dtype-independent: m121-128; lane map HW-validated by R9/R10 bf16 32x32].
__global__ __launch_bounds__(512, 1) void gemm_i8(
    const signed char* __restrict__ A, const signed char* __restrict__ B,
    const float* __restrict__ scale, const float* __restrict__ sx,
    float* __restrict__ out) {
  __shared__ __align__(16) char smw[65536];  // 2 buffers x 32 KiB
  const int tid = threadIdx.x;
  const int lane = tid & 63;
  const int wv = tid >> 6;
  const int wr = wv >> 2, wc = wv & 3;   // 2x4 wave grid, 128x64 out/wave
  const int l31 = lane & 31;
  const int h = lane >> 5;
  const int swz = ((((l31 >> 1) ^ (l31 >> 3)) & 3) << 4);  // lane-only key

  int id = blockIdx.x;                   // T1: bijective XCD swizzle
  id = (id & 7) * (NWG / 8) + (id >> 3);
  const int bn = (id % NBN) * BN;
  const int bm = (id / NBN) * BM;

  int16v acc[4][2] = {};                 // 128 accum regs (AGPR-eligible)

  // prologue: stage tile 0 (4 issues); vmcnt BEFORE barrier (visibility)
  stage_q(A, bm,       0, smw,         tid);
  stage_q(A, bm + 128, 0, smw +  8192, tid);
  stage_q(B, bn,       0, smw + 16384, tid);
  stage_q(B, bn + 128, 0, smw + 24576, tid);
  asm volatile("s_waitcnt vmcnt(0)" ::: "memory");
  __builtin_amdgcn_s_barrier();

#pragma unroll 1
  for (int t = 0; t < NT; ++t) {
    const int cur = t & 1;
    const char* Abuf = smw + cur * 32768 + wr * 8192;
    const char* Bbuf = smw + cur * 32768 + 16384 + (wc >> 1) * 8192;
    char* nb = smw + (cur ^ 1) * 32768;
    const int k1 = (t + 1) * BKB;
    const bool pf = (t + 1 < NT);

    // 2 K-halves; 6 ds_read_b128 + 8 MFMA each; prefetch spread across them
#pragma unroll
    for (int kq = 0; kq < 2; ++kq) {
      const int cb = ((kq * 2 + h) << 4) ^ swz;
      int4v af[4], bfr[2];
#pragma unroll
      for (int mi = 0; mi < 4; ++mi)
        af[mi] = *(const int4v*)(Abuf + (mi * 32 + l31) * 64 + cb);
#pragma unroll
      for (int ni = 0; ni < 2; ++ni)
        bfr[ni] = *(const int4v*)(Bbuf + (((wc & 1) * 64 + ni * 32 + l31)) * 64 + cb);
      if (pf) {
        if (kq == 0) {
          stage_q(A, bm,       k1, nb,        tid);
          stage_q(A, bm + 128, k1, nb + 8192, tid);
        } else {
          stage_q(B, bn,       k1, nb + 16384, tid);
          stage_q(B, bn + 128, k1, nb + 24576, tid);
        }
      }
      __builtin_amdgcn_s_setprio(1);
#pragma unroll
      for (int mi = 0; mi < 4; ++mi)
#pragma unroll
        for (int ni = 0; ni < 2; ++ni)
          acc[mi][ni] = __builtin_amdgcn_mfma_i32_32x32x32_i8(
              af[mi], bfr[ni], acc[mi][ni], 0, 0, 0);
      __builtin_amdgcn_s_setprio(0);
    }

    // Bottom sync: drain own prefetch (issued earlier this tile), THEN
    // barrier => all waves' tile-t+1 data visible + tile-t reads retired.
    if (pf) {
      asm volatile("s_waitcnt vmcnt(0)" ::: "memory");
      __builtin_amdgcn_s_barrier();
    }
  }

  // epilogue: y = acc * sx[row] * scale[col]; 32x32 C/D layout
  const int ocol0 = bn + wc * 64 + l31;
  const int orow0 = bm + wr * 128 + 4 * h;
#pragma unroll
  for (int ni = 0; ni < 2; ++ni) {
    const float sc = scale[ocol0 + ni * 32];
#pragma unroll
    for (int mi = 0; mi < 4; ++mi) {
#pragma unroll
      for (int reg = 0; reg < 16; ++reg) {
        const int row = orow0 + mi * 32 + (reg & 3) + 8 * (reg >> 2);
        out[(size_t)row * N_DIM + ocol0 + ni * 32] =
            (float)acc[mi][ni][reg] * sx[row] * sc;
      }
    }
  }
}

// ---- fallback (only if ws too small): fp32 LDS-tiled, correct but slow ----
__global__ __launch_bounds__(256) void gemm_fallback(
    const float* __restrict__ X, const int* __restrict__ Wq,
    const float* __restrict__ scale, float* __restrict__ out) {
  __shared__ float Xs[64][17];
  __shared__ float Ws[64][17];
  const int tid = threadIdx.x;
  const int tn = blockIdx.x % (N_DIM / 64);
  const int tm = blockIdx.x / (N_DIM / 64);
  const int tr = tid >> 4, tc = tid & 15;
  float acc[4][4] = {};
  for (int k0 = 0; k0 < K_DIM; k0 += 16) {
#pragma unroll
    for (int i = 0; i < 4; ++i) {
      int idx = tid + i * 256;
      int r = idx >> 4, c = idx & 15;
      Xs[r][c] = X[(size_t)(tm * 64 + r) * K_DIM + k0 + c];
      Ws[r][c] = (float)Wq[(size_t)(tn * 64 + r) * K_DIM + k0 + c];
    }
    __syncthreads();
#pragma unroll
    for (int kk = 0; kk < 16; ++kk)
#pragma unroll
      for (int i = 0; i < 4; ++i) {
        float a = Xs[tr * 4 + i][kk];
#pragma unroll
        for (int j = 0; j < 4; ++j) acc[i][j] += a * Ws[tc * 4 + j][kk];
      }
    __syncthreads();
  }
#pragma unroll
  for (int i = 0; i < 4; ++i)
#pragma unroll
    for (int j = 0; j < 4; ++j) {
      int row = tm * 64 + tr * 4 + i, col = tn * 64 + tc * 4 + j;
      out[(size_t)row * N_DIM + col] = acc[i][j] * scale[col];
    }
}

extern "C" void kernel_launch(void* const* d_in, const int* in_sizes, int n_in,
                              void* d_out, int out_size, void* d_ws, size_t ws_size,
                              hipStream_t stream) {
  const float* x = (const float*)d_in[0];
  const int* Wq = (const int*)d_in[1];
  const float* scale = (const float*)d_in[2];
  float* out = (float*)d_out;

  const size_t XN = (size_t)M_DIM * K_DIM;   // 33,554,432
  const size_t WN = (size_t)N_DIM * K_DIM;   // 45,088,768
  const size_t need = XN + WN + M_DIM * sizeof(float);

  if (ws_size >= need) {
    signed char* xq = (signed char*)d_ws;
    signed char* wq = xq + XN;
    float* sx = (float*)(wq + WN);
    quant_x<<<M_DIM, 256, 0, stream>>>(x, xq, sx);
    pack_w<<<(unsigned)(WN / 4096), 256, 0, stream>>>(Wq, wq);
    gemm_i8<<<NWG, 512, 0, stream>>>(xq, wq, scale, sx, out);
  } else {
    gemm_fallback<<<(N_DIM / 64) * (M_DIM / 64), 256, 0, stream>>>(x, Wq, scale, out);
  }
}

// Round 12
// 497.775 us; speedup vs baseline: 1.5659x; 1.0342x over previous
//
#include <hip/hip_runtime.h>
#include <math.h>

// QLinear via int8: y = (sum_k xq[r][k]*Wq[c][k]) * sx[r] * scale[c]
// Wq in [0,16) is EXACT in i8; only x-quantization contributes error.
#define M_DIM 8192    // BATCH*SEQ
#define N_DIM 11008   // OUT_F
#define K_DIM 4096    // IN_F

#define BM 256
#define BN 128
#define BKB 64                     // K-bytes per tile (64 i8)
#define NT (K_DIM / BKB)           // 64 K-tiles
#define NBN (N_DIM / BN)           // 86
#define NWG ((M_DIM / BM) * NBN)   // 32*86 = 2752 (divisible by 8)

// LDS per buffer: A 256x64B = 16 KiB, B 128x64B = 8 KiB -> 24 KiB; x2 = 48 KiB.
#define BUF_STRIDE 24576
#define B_OFF 16384

typedef int int4v __attribute__((ext_vector_type(4)));
typedef int int16v __attribute__((ext_vector_type(16)));

__device__ __forceinline__ void async_copy16(const void* g, void* l) {
  __builtin_amdgcn_global_load_lds(
      (const __attribute__((address_space(1))) void*)g,
      (__attribute__((address_space(3))) void*)l, 16, 0, 0);
}

// ---- x quantization: one block per row; per-row absmax -> i8 ----
__global__ __launch_bounds__(256) void quant_x(const float* __restrict__ x,
                                               signed char* __restrict__ xq,
                                               float* __restrict__ sx) {
  __shared__ float wred[4];
  const int row = blockIdx.x;
  const int tid = threadIdx.x;
  const float4* src = (const float4*)(x + (size_t)row * K_DIM) + tid * 4;
  float4 v0 = src[0], v1 = src[1], v2 = src[2], v3 = src[3];

  float m = 0.f;
#define MX4(V) m = fmaxf(m, fmaxf(fmaxf(fabsf(V.x), fabsf(V.y)), fmaxf(fabsf(V.z), fabsf(V.w))))
  MX4(v0); MX4(v1); MX4(v2); MX4(v3);
#undef MX4
#pragma unroll
  for (int off = 32; off >= 1; off >>= 1)
    m = fmaxf(m, __shfl_xor(m, off, 64));
  if ((tid & 63) == 0) wred[tid >> 6] = m;
  __syncthreads();
  float smax = fmaxf(fmaxf(wred[0], wred[1]), fmaxf(wred[2], wred[3]));
  smax = fmaxf(smax, 1e-20f);
  const float inv = 127.f / smax;

  int4v o;
#define Q4(V, G) o[G] = ((int)rintf(V.x * inv) & 255) | (((int)rintf(V.y * inv) & 255) << 8) | \
                        (((int)rintf(V.z * inv) & 255) << 16) | (((int)rintf(V.w * inv) & 255) << 24)
  Q4(v0, 0); Q4(v1, 1); Q4(v2, 2); Q4(v3, 3);
#undef Q4
  ((int4v*)(xq + (size_t)row * K_DIM))[tid] = o;
  if (tid == 0) sx[row] = smax / 127.f;
}

// ---- W pack: int32 (0..15) -> i8, 16 elems/thread ----
__global__ __launch_bounds__(256) void pack_w(const int* __restrict__ in,
                                              signed char* __restrict__ wq) {
  const int idx = blockIdx.x * 256 + threadIdx.x;
  const int4* in4 = (const int4*)in + (size_t)idx * 4;
  int4 a = in4[0], b = in4[1], c = in4[2], d = in4[3];
  int4v o;
  o[0] = a.x | (a.y << 8) | (a.z << 16) | (a.w << 24);
  o[1] = b.x | (b.y << 8) | (b.z << 16) | (b.w << 24);
  o[2] = c.x | (c.y << 8) | (c.z << 16) | (c.w << 24);
  o[3] = d.x | (d.y << 8) | (d.z << 16) | (d.w << 24);
  ((int4v*)wq)[idx] = o;
}

// Stage one 128x64B group (8 KiB): linear LDS dest, inverse-swizzled global
// source. key(r) = ((r>>1)^(r>>3))&3 on the 16B-chunk index; grow0 is a
// multiple of 128 so key depends only on rl. 1 gload_lds/thread.
__device__ __forceinline__ void stage_q(const signed char* __restrict__ P,
                                        int grow0, int k0b, char* dest, int tid) {
  const int rl = tid >> 2;                           // 0..127
  const int key = ((rl >> 1) ^ (rl >> 3)) & 3;
  const int kb = (((tid & 3) ^ key) << 4);           // pre-swizzled chunk byte
  async_copy16(&P[(size_t)(grow0 + rl) * K_DIM + k0b + kb], dest + tid * 16);
}

// ---- main GEMM: 256x128 block-tile, BKB=64, 8 waves (4x2, 64x64/wave),
// __launch_bounds__(512,4) => <=128 unified regs/wave => 2 blocks/CU.
// Independent blocks fill each other's prefetch-drain stall (the term that
// made R3-R8 phase variants neutral). R5 sync skeleton, i8 MFMA. ----
// C/D: col=lane&31, row=(reg&3)+8*(reg>>2)+4*(lane>>5) [m74/m101; R9-R11 HW-ok].
__global__ __launch_bounds__(512, 4) void gemm_i8(
    const signed char* __restrict__ A, const signed char* __restrict__ B,
    const float* __restrict__ scale, const float* __restrict__ sx,
    float* __restrict__ out) {
  __shared__ __align__(16) char smw[2 * BUF_STRIDE];  // 48 KiB
  const int tid = threadIdx.x;
  const int lane = tid & 63;
  const int wv = tid >> 6;
  const int wr = wv >> 1, wc = wv & 1;   // 4x2 wave grid, 64x64 out/wave
  const int l31 = lane & 31;
  const int h = lane >> 5;
  const int swz = ((((l31 >> 1) ^ (l31 >> 3)) & 3) << 4);  // lane-only key

  int id = blockIdx.x;                   // T1: bijective XCD swizzle
  id = (id & 7) * (NWG / 8) + (id >> 3);
  const int bn = (id % NBN) * BN;
  const int bm = (id / NBN) * BM;

  int16v acc[2][2] = {};                 // 64 accum regs

  // prologue: stage tile 0 (3 issues); vmcnt BEFORE barrier (visibility)
  stage_q(A, bm,       0, smw,          tid);
  stage_q(A, bm + 128, 0, smw +  8192,  tid);
  stage_q(B, bn,       0, smw + B_OFF,  tid);
  asm volatile("s_waitcnt vmcnt(0)" ::: "memory");
  __builtin_amdgcn_s_barrier();

#pragma unroll 1
  for (int t = 0; t < NT; ++t) {
    const int cur = t & 1;
    const char* Abuf = smw + cur * BUF_STRIDE;
    const char* Bbuf = Abuf + B_OFF;
    char* nb = smw + (cur ^ 1) * BUF_STRIDE;
    const int k1 = (t + 1) * BKB;
    const bool pf = (t + 1 < NT);

    // 2 K-halves; 4 ds_read_b128 + 4 MFMA each; prefetch spread across them
#pragma unroll
    for (int kq = 0; kq < 2; ++kq) {
      const int cb = ((kq * 2 + h) << 4) ^ swz;
      int4v af[2], bfr[2];
#pragma unroll
      for (int mi = 0; mi < 2; ++mi)
        af[mi] = *(const int4v*)(Abuf + (wr * 64 + mi * 32 + l31) * 64 + cb);
#pragma unroll
      for (int ni = 0; ni < 2; ++ni)
        bfr[ni] = *(const int4v*)(Bbuf + (wc * 64 + ni * 32 + l31) * 64 + cb);
      if (pf) {
        if (kq == 0) {
          stage_q(A, bm,       k1, nb,        tid);
          stage_q(A, bm + 128, k1, nb + 8192, tid);
        } else {
          stage_q(B, bn,       k1, nb + B_OFF, tid);
        }
      }
      __builtin_amdgcn_s_setprio(1);
#pragma unroll
      for (int mi = 0; mi < 2; ++mi)
#pragma unroll
        for (int ni = 0; ni < 2; ++ni)
          acc[mi][ni] = __builtin_amdgcn_mfma_i32_32x32x32_i8(
              af[mi], bfr[ni], acc[mi][ni], 0, 0, 0);
      __builtin_amdgcn_s_setprio(0);
    }

    // Bottom sync: drain own prefetch, THEN barrier (cross-wave visibility).
    // The drain gap is covered by the co-resident block's compute.
    if (pf) {
      asm volatile("s_waitcnt vmcnt(0)" ::: "memory");
      __builtin_amdgcn_s_barrier();
    }
  }

  // epilogue: y = acc * sx[row] * scale[col]; 32x32 C/D layout
  const int ocol0 = bn + wc * 64 + l31;
  const int orow0 = bm + wr * 64 + 4 * h;
#pragma unroll
  for (int ni = 0; ni < 2; ++ni) {
    const float sc = scale[ocol0 + ni * 32];
#pragma unroll
    for (int mi = 0; mi < 2; ++mi) {
#pragma unroll
      for (int reg = 0; reg < 16; ++reg) {
        const int row = orow0 + mi * 32 + (reg & 3) + 8 * (reg >> 2);
        out[(size_t)row * N_DIM + ocol0 + ni * 32] =
            (float)acc[mi][ni][reg] * sx[row] * sc;
      }
    }
  }
}

// ---- fallback (only if ws too small): fp32 LDS-tiled, correct but slow ----
__global__ __launch_bounds__(256) void gemm_fallback(
    const float* __restrict__ X, const int* __restrict__ Wq,
    const float* __restrict__ scale, float* __restrict__ out) {
  __shared__ float Xs[64][17];
  __shared__ float Ws[64][17];
  const int tid = threadIdx.x;
  const int tn = blockIdx.x % (N_DIM / 64);
  const int tm = blockIdx.x / (N_DIM / 64);
  const int tr = tid >> 4, tc = tid & 15;
  float acc[4][4] = {};
  for (int k0 = 0; k0 < K_DIM; k0 += 16) {
#pragma unroll
    for (int i = 0; i < 4; ++i) {
      int idx = tid + i * 256;
      int r = idx >> 4, c = idx & 15;
      Xs[r][c] = X[(size_t)(tm * 64 + r) * K_DIM + k0 + c];
      Ws[r][c] = (float)Wq[(size_t)(tn * 64 + r) * K_DIM + k0 + c];
    }
    __syncthreads();
#pragma unroll
    for (int kk = 0; kk < 16; ++kk)
#pragma unroll
      for (int i = 0; i < 4; ++i) {
        float a = Xs[tr * 4 + i][kk];
#pragma unroll
        for (int j = 0; j < 4; ++j) acc[i][j] += a * Ws[tc * 4 + j][kk];
      }
    __syncthreads();
  }
#pragma unroll
  for (int i = 0; i < 4; ++i)
#pragma unroll
    for (int j = 0; j < 4; ++j) {
      int row = tm * 64 + tr * 4 + i, col = tn * 64 + tc * 4 + j;
      out[(size_t)row * N_DIM + col] = acc[i][j] * scale[col];
    }
}

extern "C" void kernel_launch(void* const* d_in, const int* in_sizes, int n_in,
                              void* d_out, int out_size, void* d_ws, size_t ws_size,
                              hipStream_t stream) {
  const float* x = (const float*)d_in[0];
  const int* Wq = (const int*)d_in[1];
  const float* scale = (const float*)d_in[2];
  float* out = (float*)d_out;

  const size_t XN = (size_t)M_DIM * K_DIM;   // 33,554,432
  const size_t WN = (size_t)N_DIM * K_DIM;   // 45,088,768
  const size_t need = XN + WN + M_DIM * sizeof(float);

  if (ws_size >= need) {
    signed char* xq = (signed char*)d_ws;
    signed char* wq = xq + XN;
    float* sx = (float*)(wq + WN);
    quant_x<<<M_DIM, 256, 0, stream>>>(x, xq, sx);
    pack_w<<<(unsigned)(WN / 4096), 256, 0, stream>>>(Wq, wq);
    gemm_i8<<<NWG, 512, 0, stream>>>(xq, wq, scale, sx, out);
  } else {
    gemm_fallback<<<(N_DIM / 64) * (M_DIM / 64), 256, 0, stream>>>(x, Wq, scale, out);
  }
}